// Round 5
// baseline (80.047 us; speedup 1.0000x reference)
//
#include <hip/hip_runtime.h>
#include <math.h>

#ifndef M_PI
#define M_PI 3.14159265358979323846
#endif

#define NSIDE  128
#define NTHETA 511
#define MMAX   257
#define NPIX   196608
#define PCT_M  ((size_t)NTHETA * NTHETA)   // floats per m-slab (261121)
#define MN     ((size_t)MMAX * NTHETA)     // 131327
#define BINW   544                         // swizzled bin width (>= 530)
#define QSPLIT 8                           // l-partitions per m

typedef float4 f4;

// ---- one pct row, phase S = (m+3l)&3 (compile-time) ------------------------
// Window = 16B-aligned [R-4S, R-4S+2048). lane holds e = {lane*4+d, 256+lane*4+d}.
// In-row elements: rel = e - S in [0,511) -> ring t=rel, slot c = d - S + 3.
// Head (lane0, d<S) and tail (lane63,h1,d3,S==0) are out-of-row -> zeroed.
template<int S>
__device__ __forceinline__ void do_row(const float* __restrict__ Pf,
                                       float2 xv, bool lane0, bool lane63,
                                       float (&ar)[2][7], float (&ai)[2][7])
{
    f4 a0 = *(const f4*)Pf;
    f4 a1 = *(const f4*)(Pf + 256);
    if constexpr (S >= 1) { if (lane0)  a0.x = 0.f; }
    if constexpr (S >= 2) { if (lane0)  a0.y = 0.f; }
    if constexpr (S >= 3) { if (lane0)  a0.z = 0.f; }
    if constexpr (S == 0) { if (lane63) a1.w = 0.f; }
    ar[0][3-S] = fmaf(a0.x, xv.x, ar[0][3-S]);  ai[0][3-S] = fmaf(a0.x, xv.y, ai[0][3-S]);
    ar[0][4-S] = fmaf(a0.y, xv.x, ar[0][4-S]);  ai[0][4-S] = fmaf(a0.y, xv.y, ai[0][4-S]);
    ar[0][5-S] = fmaf(a0.z, xv.x, ar[0][5-S]);  ai[0][5-S] = fmaf(a0.z, xv.y, ai[0][5-S]);
    ar[0][6-S] = fmaf(a0.w, xv.x, ar[0][6-S]);  ai[0][6-S] = fmaf(a0.w, xv.y, ai[0][6-S]);
    ar[1][3-S] = fmaf(a1.x, xv.x, ar[1][3-S]);  ai[1][3-S] = fmaf(a1.x, xv.y, ai[1][3-S]);
    ar[1][4-S] = fmaf(a1.y, xv.x, ar[1][4-S]);  ai[1][4-S] = fmaf(a1.y, xv.y, ai[1][4-S]);
    ar[1][5-S] = fmaf(a1.z, xv.x, ar[1][5-S]);  ai[1][5-S] = fmaf(a1.z, xv.y, ai[1][5-S]);
    ar[1][6-S] = fmaf(a1.w, xv.x, ar[1][6-S]);  ai[1][6-S] = fmaf(a1.w, xv.y, ai[1][6-S]);
}

template<int S0>
__device__ __forceinline__ void wave_loop(const float* __restrict__ pm,
                                          int lstart, int nrows, int lane,
                                          const float2* __restrict__ xs, int xbase,
                                          float (&ar)[2][7], float (&ai)[2][7])
{
    constexpr int S1 = (S0 + 3) & 3, S2 = (S0 + 2) & 3, S3 = (S0 + 1) & 3;
    constexpr int I0 = (S0 == 0) ? 508 : 512;   // A(l+1)-A(l) in floats
    constexpr int I1 = (S1 == 0) ? 508 : 512;
    constexpr int I2 = (S2 == 0) ? 508 : 512;
    constexpr int I3 = (S3 == 0) ? 508 : 512;
    const bool lane0 = (lane == 0), lane63 = (lane == 63);
    const float* Pf = pm + (size_t)lstart * NTHETA - S0 + lane * 4;  // 16B aligned
    int l = lstart - xbase;
    const int ng = nrows >> 2;
    for (int g = 0; g < ng; ++g) {
        do_row<S0>(Pf, xs[l  ], lane0, lane63, ar, ai);  Pf += I0;
        do_row<S1>(Pf, xs[l+1], lane0, lane63, ar, ai);  Pf += I1;
        do_row<S2>(Pf, xs[l+2], lane0, lane63, ar, ai);  Pf += I2;
        do_row<S3>(Pf, xs[l+3], lane0, lane63, ar, ai);  Pf += I3;
        l += 4;
    }
    if (nrows & 3) {   // only ever 3 (the 31-row wave)
        do_row<S0>(Pf, xs[l  ], lane0, lane63, ar, ai);  Pf += I0;
        do_row<S1>(Pf, xs[l+1], lane0, lane63, ar, ai);  Pf += I1;
        do_row<S2>(Pf, xs[l+2], lane0, lane63, ar, ai);
    }
}

// ---- main: contiguous-stream partial ftm -----------------------------------
// block = (m, q): rows [q*64, +64), 2 waves x 32(31) rows. 2056 blocks.
__global__ __launch_bounds__(128)
void ftm_main(const float* __restrict__ x_re, const float* __restrict__ x_im,
              const float* __restrict__ pct, float* __restrict__ ftm_p)
{
    __shared__ float2 xs[64];
    __shared__ float  bins[2][2][BINW];       // [wave][reim][swizzled W=k+3]
    const int m = blockIdx.x >> 3;
    const int q = blockIdx.x & 7;
    const int tid = threadIdx.x;
    const int w = tid >> 6, lane = tid & 63;
    const int rbase = q * 64;
    const int rcount = min(64, NTHETA - rbase);

    if (tid < rcount) {
        int l = rbase + tid;
        xs[tid] = make_float2(x_re[(size_t)l * MMAX + m], x_im[(size_t)l * MMAX + m]);
    }
    for (int i = tid; i < 2 * 2 * BINW; i += 128) ((float*)bins)[i] = 0.f;
    __syncthreads();

    const int lstart = rbase + w * 32;
    const int nrows  = min(32, NTHETA - lstart);   // 32, or 31 for (q7,w1)

    float ar[2][7], ai[2][7];
    #pragma unroll
    for (int h = 0; h < 2; ++h)
        #pragma unroll
        for (int c = 0; c < 7; ++c) { ar[h][c] = 0.f; ai[h][c] = 0.f; }

    const float* pm = pct + (size_t)m * PCT_M;
    switch (m & 3) {
        case 0: wave_loop<0>(pm, lstart, nrows, lane, xs, rbase, ar, ai); break;
        case 1: wave_loop<1>(pm, lstart, nrows, lane, xs, rbase, ar, ai); break;
        case 2: wave_loop<2>(pm, lstart, nrows, lane, xs, rbase, ar, ai); break;
        case 3: wave_loop<3>(pm, lstart, nrows, lane, xs, rbase, ar, ai); break;
    }

    // scatter 28 slots into this wave's bins (sequential RMW, lanes disjoint)
    #pragma unroll
    for (int h = 0; h < 2; ++h)
        #pragma unroll
        for (int c = 0; c < 7; ++c) {
            int W = h * 256 + 4 * lane + c;        // = ring + 3
            int idx = W + (W >> 5);                // bank de-swizzle
            bins[w][0][idx] += ar[h][c];
            bins[w][1][idx] += ai[h][c];
        }
    __syncthreads();

    float* dst = ftm_p + ((size_t)(q * 2) * MMAX + m) * NTHETA;
    for (int t = tid; t < NTHETA; t += 128) {
        int W = t + 3, idx = W + (W >> 5);
        dst[t]      = bins[0][0][idx] + bins[1][0][idx];
        dst[MN + t] = bins[0][1][idx] + bins[1][1][idx];
    }
}

// ---- cleanup: rows with phase s in {2,3} miss rings {510} / {509,510}.
// Output only consumes rings 509/510 for harmonics m<=4 -> 10 tiny dot products.
__global__ __launch_bounds__(640)
void cleanup(const float* __restrict__ x_re, const float* __restrict__ x_im,
             const float* __restrict__ pct, float* __restrict__ extra)
{
    const int job = threadIdx.x >> 6;     // 0..9
    const int lane = threadIdx.x & 63;
    const int tt = job / 5;               // 0 -> t=509, 1 -> t=510
    const int m  = job % 5;
    const int t  = 509 + tt;
    float sre = 0.f, sim = 0.f;
    for (int l = lane; l < NTHETA; l += 64) {
        int s = (m + 3 * l) & 3;
        bool take = tt ? (s >= 2) : (s == 3);
        if (take) {
            float v = pct[(size_t)m * PCT_M + (size_t)l * NTHETA + t];
            sre += x_re[(size_t)l * MMAX + m] * v;
            sim += x_im[(size_t)l * MMAX + m] * v;
        }
    }
    #pragma unroll
    for (int off = 32; off; off >>= 1) {
        sre += __shfl_down(sre, off);
        sim += __shfl_down(sim, off);
    }
    if (lane == 0) {
        extra[(0 * 2 + tt) * 5 + m] = sre;
        extra[(1 * 2 + tt) * 5 + m] = sim;
    }
}

// ---- combine: ftm_c[reim][m][t] = sum_q partials (+ cleanup extras) --------
__global__ __launch_bounds__(256)
void combine(const float* __restrict__ ftm_p, const float* __restrict__ extra,
             float* __restrict__ ftm_c)
{
    const size_t i = (size_t)blockIdx.x * 256 + threadIdx.x;
    if (i >= 2 * MN) return;
    const int reim = (int)(i / MN);
    const size_t rem = i % MN;             // m*511 + t
    const int m = (int)(rem / NTHETA), t = (int)(rem % NTHETA);
    float s = 0.f;
    #pragma unroll
    for (int q = 0; q < QSPLIT; ++q) s += ftm_p[(size_t)(q * 2 + reim) * MN + rem];
    if (t >= 509 && m <= 4) s += extra[(reim * 2 + (t - 509)) * 5 + m];
    ftm_c[i] = s;
}

// ---- ring: direct inverse rFFT per ring at pixel azimuths ------------------
__global__ __launch_bounds__(256)
void ring_kernel(const float* __restrict__ ftm_c, float* __restrict__ out)
{
    const int t = blockIdx.y;
    int nphi, cum;
    double phi0;
    if (t < NSIDE - 1) {
        nphi = 4 * (t + 1);
        cum  = 2 * t * (t + 1);
        phi0 = M_PI / (4.0 * (t + 1));
    } else if (t <= 3 * NSIDE - 1) {
        nphi = 4 * NSIDE;
        cum  = 2 * (NSIDE - 1) * NSIDE + (t - (NSIDE - 1)) * 4 * NSIDE;
        phi0 = (M_PI / (2.0 * NSIDE)) * (0.5 * (double)((t - NSIDE + 2) % 2));
    } else {
        int s = 4 * NSIDE - 1 - t;
        nphi = 4 * s;
        cum  = NPIX - 2 * s * (s + 1);
        phi0 = M_PI / (4.0 * s);
    }
    if ((int)blockIdx.x * 256 >= nphi) return;

    const int mtop = nphi / 2;
    __shared__ float fr[MMAX];
    __shared__ float fi[MMAX];
    for (int i = threadIdx.x; i <= mtop; i += 256) {
        fr[i] = ftm_c[(size_t)i * NTHETA + t];
        fi[i] = ftm_c[MN + (size_t)i * NTHETA + t];
    }
    __syncthreads();

    const int k = blockIdx.x * 256 + threadIdx.x;
    if (k >= nphi) return;

    double phi = phi0 + (2.0 * M_PI) * ((double)k / (double)nphi);
    float sp, cp;
    sincosf((float)phi, &sp, &cp);

    float cr = 1.f, ci = 0.f;
    float acc = fr[0];
    for (int mm = 1; mm < mtop; ++mm) {
        float nr = cr * cp - ci * sp;
        float ni = cr * sp + ci * cp;
        cr = nr; ci = ni;
        acc += 2.f * (fr[mm] * cr - fi[mm] * ci);
    }
    {
        float nr = cr * cp - ci * sp;
        float ni = cr * sp + ci * cp;
        acc += fr[mtop] * nr - fi[mtop] * ni;
    }
    out[cum + k] = acc;
}

extern "C" void kernel_launch(void* const* d_in, const int* in_sizes, int n_in,
                              void* d_out, int out_size, void* d_ws, size_t ws_size,
                              hipStream_t stream)
{
    const float* x_re = (const float*)d_in[0];
    const float* x_im = (const float*)d_in[1];
    const float* pct  = (const float*)d_in[2];
    float* out = (float*)d_out;

    float* ftm_p = (float*)d_ws;                       // [8][2][257][511]
    float* ftm_c = ftm_p + (size_t)QSPLIT * 2 * MN;    // [2][257][511]
    float* extra = ftm_c + 2 * MN;                     // [2][2][5]

    ftm_main<<<dim3(MMAX * QSPLIT), 128, 0, stream>>>(x_re, x_im, pct, ftm_p);
    cleanup <<<dim3(1), 640, 0, stream>>>(x_re, x_im, pct, extra);
    combine <<<dim3((unsigned)((2 * MN + 255) / 256)), 256, 0, stream>>>(ftm_p, extra, ftm_c);
    ring_kernel<<<dim3(2, NTHETA), 256, 0, stream>>>(ftm_c, out);
}

// Round 6
// 63.619 us; speedup vs baseline: 1.2582x; 1.2582x over previous
//
#include <hip/hip_runtime.h>
#include <math.h>

#ifndef M_PI
#define M_PI 3.14159265358979323846
#endif

#define NSIDE  128
#define NTHETA 511            // = LMAX = number of rings
#define MMAX   257
#define NPIX   196608
#define KSPLIT 4              // equal k-chunks per m (load balance granularity)

// Kernel 1: ftm[k][m] = sum_l x[l][m] * pct[m][l][k], computed ONLY for
// k in [klo(m), 510-klo(m)] where klo = ceil(m/2)-1  (ring k consumes
// harmonic m iff nphi(k) >= 2m). Cuts pct traffic 268 MB -> 202 MB.
// Block = (m, j): j-th of 4 equal chunks of the valid k-range.
__global__ __launch_bounds__(128)
void ftm_kernel(const float* __restrict__ x_re,
                const float* __restrict__ x_im,
                const float* __restrict__ pct,
                float* __restrict__ ftm_re,
                float* __restrict__ ftm_im)
{
    const int m  = blockIdx.x >> 2;          // 0..256
    const int j  = blockIdx.x & 3;
    const int klo = (m >= 2) ? ((m + 1) / 2 - 1) : 0;
    const int cnt = NTHETA - 2 * klo;        // valid columns (257..511)
    const int lo  = klo + (cnt * j) / KSPLIT;
    const int hi  = klo + (cnt * (j + 1)) / KSPLIT;   // chunk <= 128 cols

    __shared__ float xr[NTHETA];
    __shared__ float xi[NTHETA];
    const int tid = threadIdx.x;
    for (int i = tid; i < NTHETA; i += 128) {
        xr[i] = x_re[(size_t)i * MMAX + m];
        xi[i] = x_im[(size_t)i * MMAX + m];
    }
    __syncthreads();

    const int k = lo + tid;
    if (k >= hi) return;

    const float* p = pct + (size_t)m * NTHETA * NTHETA + k;
    float ar = 0.f, ai = 0.f;

    int l = 0;
    for (; l <= NTHETA - 8; l += 8) {
        float v[8];
        #pragma unroll
        for (int u = 0; u < 8; ++u) v[u] = p[(size_t)(l + u) * NTHETA];
        #pragma unroll
        for (int u = 0; u < 8; ++u) {
            ar = fmaf(xr[l + u], v[u], ar);
            ai = fmaf(xi[l + u], v[u], ai);
        }
    }
    {   // batched tail: rows 504..510 (7 loads issued together)
        float v[7];
        #pragma unroll
        for (int u = 0; u < 7; ++u) v[u] = p[(size_t)(504 + u) * NTHETA];
        #pragma unroll
        for (int u = 0; u < 7; ++u) {
            ar = fmaf(xr[504 + u], v[u], ar);
            ai = fmaf(xi[504 + u], v[u], ai);
        }
    }

    ftm_re[(size_t)k * MMAX + m] = ar;
    ftm_im[(size_t)k * MMAX + m] = ai;
}

// Kernel 2: direct inverse rFFT per ring at pixel azimuths (unchanged R1).
// f[cum+k] = fr[0] + 2*sum_{m=1}^{N/2-1} (fr[m]*cos(m*phi) - fi[m]*sin(m*phi))
//                  +     (fr[N/2]*cos(..) - fi[N/2]*sin(..))
// with phi = phi0(t) + 2*pi*k/nphi. Reads fr/fi only for m <= nphi/2 --
// exactly the slots ftm_kernel writes.
__global__ __launch_bounds__(256)
void ring_kernel(const float* __restrict__ ftm_re,
                 const float* __restrict__ ftm_im,
                 float* __restrict__ out)
{
    const int t = blockIdx.y;
    int nphi, cum;
    double phi0;
    if (t < NSIDE - 1) {                       // north polar cap
        nphi = 4 * (t + 1);
        cum  = 2 * t * (t + 1);
        phi0 = M_PI / (4.0 * (t + 1));
    } else if (t <= 3 * NSIDE - 1) {           // equatorial belt
        nphi = 4 * NSIDE;
        cum  = 2 * (NSIDE - 1) * NSIDE + (t - (NSIDE - 1)) * 4 * NSIDE;
        phi0 = (M_PI / (2.0 * NSIDE)) * (0.5 * (double)((t - NSIDE + 2) % 2));
    } else {                                   // south polar cap
        int s = 4 * NSIDE - 1 - t;
        nphi = 4 * s;
        cum  = NPIX - 2 * s * (s + 1);
        phi0 = M_PI / (4.0 * s);
    }
    if ((int)blockIdx.x * 256 >= nphi) return;  // block-uniform early exit

    const int mtop = nphi / 2;                  // inclusive top harmonic (<= 256)
    __shared__ float fr[MMAX];
    __shared__ float fi[MMAX];
    for (int i = threadIdx.x; i <= mtop; i += 256) {
        fr[i] = ftm_re[(size_t)t * MMAX + i];
        fi[i] = ftm_im[(size_t)t * MMAX + i];
    }
    __syncthreads();

    const int k = blockIdx.x * 256 + threadIdx.x;
    if (k >= nphi) return;

    double phi = phi0 + (2.0 * M_PI) * ((double)k / (double)nphi);
    float sp, cp;
    sincosf((float)phi, &sp, &cp);

    float cr = 1.f, ci = 0.f;                   // e^{i*m*phi}, m=0
    float acc = fr[0];
    for (int m = 1; m < mtop; ++m) {
        float nr = cr * cp - ci * sp;
        float ni = cr * sp + ci * cp;
        cr = nr; ci = ni;
        acc += 2.f * (fr[m] * cr - fi[m] * ci);
    }
    {   // m = mtop, weight 1
        float nr = cr * cp - ci * sp;
        float ni = cr * sp + ci * cp;
        acc += fr[mtop] * nr - fi[mtop] * ni;
    }
    out[cum + k] = acc;
}

extern "C" void kernel_launch(void* const* d_in, const int* in_sizes, int n_in,
                              void* d_out, int out_size, void* d_ws, size_t ws_size,
                              hipStream_t stream)
{
    const float* x_re = (const float*)d_in[0];
    const float* x_im = (const float*)d_in[1];
    const float* pct  = (const float*)d_in[2];
    float* out = (float*)d_out;

    float* ftm_re = (float*)d_ws;                       // NTHETA*MMAX floats
    float* ftm_im = ftm_re + (size_t)NTHETA * MMAX;     // NTHETA*MMAX floats

    ftm_kernel<<<dim3(MMAX * KSPLIT), 128, 0, stream>>>(x_re, x_im, pct, ftm_re, ftm_im);
    ring_kernel<<<dim3(2, NTHETA), 256, 0, stream>>>(ftm_re, ftm_im, out);
}